// Round 2
// baseline (293.185 us; speedup 1.0000x reference)
//
#include <hip/hip_runtime.h>

// Problem constants (from reference): J=6 blocks, B=16 batch, C=2 classes, H=W=512.
#define NJ 6
#define NB 16
#define NP (512 * 512)      // pixels per (j,b) plane
#define NPV (NP / 4)        // float4 vec-units per plane = 65536
#define NTOT ((double)NJ * NB * NP)

// stable softplus: log(1 + exp(x))
__device__ __forceinline__ float softplus(float x) {
    return fmaxf(x, 0.0f) + log1pf(expf(-fabsf(x)));
}

__global__ __launch_bounds__(256) void ce_partial_kernel(
        const float* __restrict__ logits,   // [J][B][2][H][W]
        const int*   __restrict__ target,   // [B][H][W]
        double*      __restrict__ accum) {
    const int totalVec = NB * NPV;          // 1,048,576 vec-units (b, pixel/4)
    float tsum = 0.0f;

    for (int u = blockIdx.x * blockDim.x + threadIdx.x; u < totalVec;
         u += gridDim.x * blockDim.x) {
        const int b  = u >> 16;             // NPV = 65536
        const int pv = u & 65535;

        const int4 t4 = *reinterpret_cast<const int4*>(
            target + (size_t)b * NP + (size_t)pv * 4);

        #pragma unroll
        for (int j = 0; j < NJ; ++j) {
            const float* base = logits
                + (size_t)(j * NB + b) * 2 * NP + (size_t)pv * 4;
            const float4 l0 = *reinterpret_cast<const float4*>(base);        // class 0
            const float4 l1 = *reinterpret_cast<const float4*>(base + NP);   // class 1

            // nll = logsumexp(l0,l1) - l_target = softplus(l_other - l_target)
            const float x0 = (t4.x == 0) ? (l1.x - l0.x) : (l0.x - l1.x);
            const float x1 = (t4.y == 0) ? (l1.y - l0.y) : (l0.y - l1.y);
            const float x2 = (t4.z == 0) ? (l1.z - l0.z) : (l0.z - l1.z);
            const float x3 = (t4.w == 0) ? (l1.w - l0.w) : (l0.w - l1.w);

            tsum += softplus(x0) + softplus(x1) + softplus(x2) + softplus(x3);
        }
    }

    // wave (64-lane) shuffle reduction
    #pragma unroll
    for (int off = 32; off > 0; off >>= 1)
        tsum += __shfl_down(tsum, off, 64);

    __shared__ double warp_part[4];         // 256 threads = 4 waves
    const int lane = threadIdx.x & 63;
    const int wid  = threadIdx.x >> 6;
    if (lane == 0) warp_part[wid] = (double)tsum;
    __syncthreads();

    if (threadIdx.x == 0) {
        double s = warp_part[0] + warp_part[1] + warp_part[2] + warp_part[3];
        atomicAdd(accum, s);                // device-scope f64 atomic (CDNA-native)
    }
}

__global__ void ce_final_kernel(const double* __restrict__ accum,
                                float* __restrict__ out) {
    if (threadIdx.x == 0 && blockIdx.x == 0) {
        out[0] = (float)(accum[0] / NTOT);
    }
}

extern "C" void kernel_launch(void* const* d_in, const int* in_sizes, int n_in,
                              void* d_out, int out_size, void* d_ws, size_t ws_size,
                              hipStream_t stream) {
    const float* logits = (const float*)d_in[0];
    const int*   target = (const int*)d_in[1];
    float*       out    = (float*)d_out;
    double*      accum  = (double*)d_ws;

    hipMemsetAsync(accum, 0, sizeof(double), stream);

    // 2048 blocks x 256 threads = 524,288 threads; 1,048,576 vec-units -> 2 iters/thread
    ce_partial_kernel<<<2048, 256, 0, stream>>>(logits, target, accum);
    ce_final_kernel<<<1, 64, 0, stream>>>(accum, out);
}

// Round 3
// 291.495 us; speedup vs baseline: 1.0058x; 1.0058x over previous
//
#include <hip/hip_runtime.h>

// Problem constants (from reference): J=6 blocks, B=16 batch, C=2 classes, H=W=512.
#define NJ 6
#define NB 16
#define NP (512 * 512)      // pixels per (j,b) plane
#define NPV (NP / 4)        // float4 vec-units per plane = 65536
#define NTOT ((double)NJ * NB * NP)
#define NBLOCKS 2048

// stable softplus: log(1 + exp(x))
__device__ __forceinline__ float softplus(float x) {
    return fmaxf(x, 0.0f) + log1pf(expf(-fabsf(x)));
}

__global__ __launch_bounds__(256) void ce_partial_kernel(
        const float* __restrict__ logits,   // [J][B][2][H][W]
        const int*   __restrict__ target,   // [B][H][W]
        double*      __restrict__ partials) // [NBLOCKS], one slot per block
{
    const int totalVec = NB * NPV;          // 1,048,576 vec-units (b, pixel/4)
    float tsum = 0.0f;

    for (int u = blockIdx.x * blockDim.x + threadIdx.x; u < totalVec;
         u += gridDim.x * blockDim.x) {
        const int b  = u >> 16;             // NPV = 65536
        const int pv = u & 65535;

        const int4 t4 = *reinterpret_cast<const int4*>(
            target + (size_t)b * NP + (size_t)pv * 4);

        #pragma unroll
        for (int j = 0; j < NJ; ++j) {
            const float* base = logits
                + (size_t)(j * NB + b) * 2 * NP + (size_t)pv * 4;
            const float4 l0 = *reinterpret_cast<const float4*>(base);        // class 0
            const float4 l1 = *reinterpret_cast<const float4*>(base + NP);   // class 1

            // nll = logsumexp(l0,l1) - l_target = softplus(l_other - l_target)
            const float x0 = (t4.x == 0) ? (l1.x - l0.x) : (l0.x - l1.x);
            const float x1 = (t4.y == 0) ? (l1.y - l0.y) : (l0.y - l1.y);
            const float x2 = (t4.z == 0) ? (l1.z - l0.z) : (l0.z - l1.z);
            const float x3 = (t4.w == 0) ? (l1.w - l0.w) : (l0.w - l1.w);

            tsum += softplus(x0) + softplus(x1) + softplus(x2) + softplus(x3);
        }
    }

    // wave (64-lane) shuffle reduction
    #pragma unroll
    for (int off = 32; off > 0; off >>= 1)
        tsum += __shfl_down(tsum, off, 64);

    __shared__ double warp_part[4];         // 256 threads = 4 waves
    const int lane = threadIdx.x & 63;
    const int wid  = threadIdx.x >> 6;
    if (lane == 0) warp_part[wid] = (double)tsum;
    __syncthreads();

    // Every block writes its slot unconditionally -> no init/memset needed,
    // even though the harness poisons d_ws to 0xAA before each launch.
    if (threadIdx.x == 0) {
        partials[blockIdx.x] =
            warp_part[0] + warp_part[1] + warp_part[2] + warp_part[3];
    }
}

__global__ __launch_bounds__(256) void ce_final_kernel(
        const double* __restrict__ partials,
        float* __restrict__ out)
{
    // 2048 partials, 256 threads -> 8 each
    double s = 0.0;
    #pragma unroll
    for (int k = 0; k < NBLOCKS / 256; ++k)
        s += partials[threadIdx.x + k * 256];

    #pragma unroll
    for (int off = 32; off > 0; off >>= 1)
        s += __shfl_down(s, off, 64);

    __shared__ double warp_part[4];
    const int lane = threadIdx.x & 63;
    const int wid  = threadIdx.x >> 6;
    if (lane == 0) warp_part[wid] = s;
    __syncthreads();

    if (threadIdx.x == 0) {
        out[0] = (float)((warp_part[0] + warp_part[1] +
                          warp_part[2] + warp_part[3]) / NTOT);
    }
}

extern "C" void kernel_launch(void* const* d_in, const int* in_sizes, int n_in,
                              void* d_out, int out_size, void* d_ws, size_t ws_size,
                              hipStream_t stream) {
    const float* logits   = (const float*)d_in[0];
    const int*   target   = (const int*)d_in[1];
    float*       out      = (float*)d_out;
    double*      partials = (double*)d_ws;   // 2048 * 8 B = 16 KB of scratch

    ce_partial_kernel<<<NBLOCKS, 256, 0, stream>>>(logits, target, partials);
    ce_final_kernel<<<1, 256, 0, stream>>>(partials, out);
}

// Round 5
// 289.825 us; speedup vs baseline: 1.0116x; 1.0058x over previous
//
#include <hip/hip_runtime.h>

// Problem constants (from reference): J=6 blocks, B=16 batch, C=2 classes, H=W=512.
#define NJ 6
#define NB 16
#define NP (512 * 512)      // pixels per (j,b) plane
#define NPV (NP / 4)        // float4 vec-units per plane = 65536
#define NTOT ((double)NJ * NB * NP)
#define NBLOCKS 4096        // 1,048,576 vec-units / 256 threads = 4096 blocks, 1 unit/thread

// stable softplus: log(1 + exp(x))
__device__ __forceinline__ float softplus(float x) {
    return fmaxf(x, 0.0f) + log1pf(expf(-fabsf(x)));
}

__global__ __launch_bounds__(256) void ce_partial_kernel(
        const float* __restrict__ logits,   // [J][B][2][H][W]
        const int*   __restrict__ target,   // [B][H][W]
        double*      __restrict__ partials) // [NBLOCKS], one slot per block
{
    // exactly one float4-unit per thread: u in [0, NB*NPV)
    const int u  = blockIdx.x * 256 + threadIdx.x;
    const int b  = u >> 16;                 // NPV = 65536
    const int pv = u & 65535;

    const int4 t4 = *reinterpret_cast<const int4*>(
        target + (size_t)b * NP + (size_t)pv * 4);

    float tsum = 0.0f;
    #pragma unroll
    for (int j = 0; j < NJ; ++j) {
        const float* base = logits
            + (size_t)(j * NB + b) * 2 * NP + (size_t)pv * 4;
        const float4 l0 = *reinterpret_cast<const float4*>(base);        // class 0
        const float4 l1 = *reinterpret_cast<const float4*>(base + NP);   // class 1

        // nll = logsumexp(l0,l1) - l_target = softplus(l_other - l_target)
        const float x0 = (t4.x == 0) ? (l1.x - l0.x) : (l0.x - l1.x);
        const float x1 = (t4.y == 0) ? (l1.y - l0.y) : (l0.y - l1.y);
        const float x2 = (t4.z == 0) ? (l1.z - l0.z) : (l0.z - l1.z);
        const float x3 = (t4.w == 0) ? (l1.w - l0.w) : (l0.w - l1.w);

        tsum += softplus(x0) + softplus(x1) + softplus(x2) + softplus(x3);
    }

    // wave (64-lane) shuffle reduction
    #pragma unroll
    for (int off = 32; off > 0; off >>= 1)
        tsum += __shfl_down(tsum, off, 64);

    __shared__ double warp_part[4];         // 256 threads = 4 waves
    const int lane = threadIdx.x & 63;
    const int wid  = threadIdx.x >> 6;
    if (lane == 0) warp_part[wid] = (double)tsum;
    __syncthreads();

    // Every block writes its slot unconditionally -> no init/memset needed,
    // even though the harness poisons d_ws to 0xAA before each launch.
    if (threadIdx.x == 0) {
        partials[blockIdx.x] =
            warp_part[0] + warp_part[1] + warp_part[2] + warp_part[3];
    }
}

__global__ __launch_bounds__(256) void ce_final_kernel(
        const double* __restrict__ partials,
        float* __restrict__ out)
{
    // 4096 partials, 256 threads -> 16 each
    double s = 0.0;
    #pragma unroll
    for (int k = 0; k < NBLOCKS / 256; ++k)
        s += partials[threadIdx.x + k * 256];

    #pragma unroll
    for (int off = 32; off > 0; off >>= 1)
        s += __shfl_down(s, off, 64);

    __shared__ double warp_part[4];
    const int lane = threadIdx.x & 63;
    const int wid  = threadIdx.x >> 6;
    if (lane == 0) warp_part[wid] = s;
    __syncthreads();

    if (threadIdx.x == 0) {
        out[0] = (float)((warp_part[0] + warp_part[1] +
                          warp_part[2] + warp_part[3]) / NTOT);
    }
}

extern "C" void kernel_launch(void* const* d_in, const int* in_sizes, int n_in,
                              void* d_out, int out_size, void* d_ws, size_t ws_size,
                              hipStream_t stream) {
    const float* logits   = (const float*)d_in[0];
    const int*   target   = (const int*)d_in[1];
    float*       out      = (float*)d_out;
    double*      partials = (double*)d_ws;   // 4096 * 8 B = 32 KB of scratch

    ce_partial_kernel<<<NBLOCKS, 256, 0, stream>>>(logits, target, partials);
    ce_final_kernel<<<1, 256, 0, stream>>>(partials, out);
}